// Round 1
// baseline (257.649 us; speedup 1.0000x reference)
//
#include <hip/hip_runtime.h>

#define L_FFT 4096
#define NMODE 64
#define NCH 512      // H*E
#define NROW 8192    // B*H*E rows

// ---------------------------------------------------------------------------
// K0: trig tables.
// T1 [4096][128]: cols 0..63 = cos(2*pi*l*index[m]/L), cols 64..127 = -sin(...)
//   (sign folded so forward GEMM produces g_im directly)
// T2 [128][4096]: rows 0..63 = cos(2*pi*m*l/L), rows 64..127 = +sin(...)
//   (inverse frequencies are the slot index m, not index[m])
// ---------------------------------------------------------------------------
__global__ __launch_bounds__(256) void k0_tables(const int* __restrict__ index,
                                                 float* __restrict__ T1,
                                                 float* __restrict__ T2) {
  int idx = blockIdx.x * 256 + threadIdx.x;  // 0..262143
  const float w0 = 6.2831853071795864769f / (float)L_FFT;
  {
    int l = idx >> 6, m = idx & 63;
    int f = index[m];
    int ph = (l * f) & (L_FFT - 1);
    float s, c;
    sincosf(w0 * (float)ph, &s, &c);
    T1[l * 128 + m] = c;
    T1[l * 128 + 64 + m] = -s;
  }
  {
    int m2 = idx >> 12, l2 = idx & (L_FFT - 1);
    int ph = (m2 * l2) & (L_FFT - 1);
    float s, c;
    sincosf(w0 * (float)ph, &s, &c);
    T2[m2 * L_FFT + l2] = c;
    T2[(64 + m2) * L_FFT + l2] = s;
  }
}

// ---------------------------------------------------------------------------
// K1: forward DFT GEMM.  part[p][c][k] = sum_{l in span p} X[c,l] * T1[l,k]
// X[c,l] = q[b, l, ch]  with c = b*512 + ch  (q layout [B,L,H,E], ch = h*64+i)
// Tile: 128 channels x 128 outputs, K-chunk 32, 256 threads, micro 8c x (4+4)m.
// ---------------------------------------------------------------------------
__global__ __launch_bounds__(256) void k1_forward(const float* __restrict__ q,
                                                  const float* __restrict__ T1,
                                                  float* __restrict__ part,
                                                  int kspan) {
  int ctile = blockIdx.x;            // 0..63
  int p = blockIdx.y;                // 0..np-1
  int b = ctile >> 2;                // 4 tiles of 128 per b (512 ch)
  int ch0 = (ctile & 3) * 128;
  int l0base = p * kspan;

  __shared__ float Xs[32][128];      // 16 KB
  __shared__ float Ts[32][128];      // 16 KB

  int t = threadIdx.x;
  int cg = t >> 4;                   // 0..15 -> c_sub = cg*8
  int mg = t & 15;                   // outputs mg*4..+3 and 64+mg*4..+3
  float acc[8][8] = {};

  for (int l0 = l0base; l0 < l0base + kspan; l0 += 32) {
#pragma unroll
    for (int j = 0; j < 16; ++j) {
      int idx = j * 256 + t;
      int lr = idx >> 7, cr = idx & 127;
      Xs[lr][cr] = q[((size_t)b * L_FFT + l0 + lr) * NCH + ch0 + cr];
    }
#pragma unroll
    for (int j = 0; j < 16; ++j) {
      int idx = j * 256 + t;
      int lr = idx >> 7, kr = idx & 127;
      Ts[lr][kr] = T1[(l0 + lr) * 128 + kr];
    }
    __syncthreads();
#pragma unroll 8
    for (int l = 0; l < 32; ++l) {
      float xv[8], tv[8];
      *(float4*)&xv[0] = *(const float4*)&Xs[l][cg * 8];
      *(float4*)&xv[4] = *(const float4*)&Xs[l][cg * 8 + 4];
      *(float4*)&tv[0] = *(const float4*)&Ts[l][mg * 4];
      *(float4*)&tv[4] = *(const float4*)&Ts[l][64 + mg * 4];
#pragma unroll
      for (int i = 0; i < 8; ++i)
#pragma unroll
        for (int jj = 0; jj < 8; ++jj)
          acc[i][jj] = fmaf(xv[i], tv[jj], acc[i][jj]);
    }
    __syncthreads();
  }

  int base_c = ctile * 128 + cg * 8;
#pragma unroll
  for (int i = 0; i < 8; ++i) {
    float* dst = &part[(size_t)p * 1048576 + (size_t)(base_c + i) * 128];
    *(float4*)(dst + mg * 4) =
        make_float4(acc[i][0], acc[i][1], acc[i][2], acc[i][3]);
    *(float4*)(dst + 64 + mg * 4) =
        make_float4(acc[i][4], acc[i][5], acc[i][6], acc[i][7]);
  }
}

// K1b: reduce split-K partials -> g [8192][128]
__global__ __launch_bounds__(256) void k1b_reduce(const float* __restrict__ part,
                                                  float* __restrict__ g, int np) {
  int idx = blockIdx.x * 256 + threadIdx.x;  // < 1048576
  float s = 0.f;
  for (int p = 0; p < np; ++p) s += part[(size_t)p * 1048576 + idx];
  g[idx] = s;
}

// ---------------------------------------------------------------------------
// K2: mode mix + irfft coefficient prep.
// out[b,h,o,m] = sum_i g[b,h,i,m] * w[h,i,o,m]   (complex)
// A[c'][m]      = Re(out)* (m==0 ? 1 : 2)/L
// A[c'][64+m]   = (m==0 ? 0 : -2/L * Im(out))
// g rows are c = b*512 + h*64 + i; cols 0..63 = g_re, 64..127 = g_im (sign folded in T1).
// ---------------------------------------------------------------------------
__global__ __launch_bounds__(256) void k2_mix(const float* __restrict__ g,
                                              const float* __restrict__ wre,
                                              const float* __restrict__ wim,
                                              float* __restrict__ A) {
  int oq = blockIdx.x;  // 16
  int h = blockIdx.y;   // 8
  int b = blockIdx.z;   // 16
  __shared__ float gre[64][64], gim[64][64];  // 32 KB
  int t = threadIdx.x;
  int bh = b * 8 + h;
#pragma unroll
  for (int j = 0; j < 16; ++j) {
    int idx = j * 256 + t, ir = idx >> 6, mr = idx & 63;
    const float* row = &g[((size_t)bh * 64 + ir) * 128];
    gre[ir][mr] = row[mr];
    gim[ir][mr] = row[64 + mr];
  }
  __syncthreads();
  int o = oq * 4 + (t >> 6), m = t & 63;
  float are = 0.f, aim = 0.f;
  for (int i = 0; i < 64; ++i) {
    float gr = gre[i][m], gi = gim[i][m];
    int wofs = ((h * 64 + i) * 64 + o) * 64 + m;
    float wr = wre[wofs], wi = wim[wofs];
    are = fmaf(gr, wr, are);
    are = fmaf(-gi, wi, are);
    aim = fmaf(gr, wi, aim);
    aim = fmaf(gi, wr, aim);
  }
  const float invL = 1.0f / (float)L_FFT;
  float outre = are * ((m == 0) ? invL : 2.0f * invL);
  float outim = (m == 0) ? 0.0f : (-2.0f * invL) * aim;
  float* dst = &A[((size_t)bh * 64 + o) * 128];
  dst[m] = outre;
  dst[64 + m] = outim;
}

// ---------------------------------------------------------------------------
// K3: inverse GEMM.  y[c'][l] = sum_{k=0}^{127} A[c'][k] * T2[k][l]
// Tile 64 c' x 256 l, K chunked by 32.  A staged transposed [k][c] (pad 68)
// so per-k fragment reads are contiguous b128 broadcasts.
// Thread outputs: l = l0 + lg*4 + {0..3} and l0 + 128 + lg*4 + {0..3}.
// ---------------------------------------------------------------------------
__global__ __launch_bounds__(256) void k3_inverse(const float* __restrict__ A,
                                                  const float* __restrict__ T2,
                                                  float* __restrict__ y) {
  int l0 = blockIdx.x * 256;  // 16 tiles
  int c0 = blockIdx.y * 64;   // 128 tiles
  __shared__ float As[128][68];    // ~34 KB, [k][c] padded (272 B rows, 16B-aligned)
  __shared__ float T2s[32][256];   // 32 KB
  int t = threadIdx.x;

#pragma unroll
  for (int j = 0; j < 32; ++j) {
    int idx = j * 256 + t;  // 8192
    int cr = idx >> 7, kr = idx & 127;
    As[kr][cr] = A[((size_t)c0 + cr) * 128 + kr];
  }

  float acc[8][8] = {};
  int lg = t & 31, cg = t >> 5;

  for (int kc = 0; kc < 128; kc += 32) {
#pragma unroll
    for (int j = 0; j < 32; ++j) {
      int idx = j * 256 + t;
      int kr = idx >> 8, lr = idx & 255;
      T2s[kr][lr] = T2[(size_t)(kc + kr) * L_FFT + l0 + lr];
    }
    __syncthreads();
#pragma unroll 8
    for (int k = 0; k < 32; ++k) {
      float av[8], tv[8];
      *(float4*)&av[0] = *(const float4*)&As[kc + k][cg * 8];
      *(float4*)&av[4] = *(const float4*)&As[kc + k][cg * 8 + 4];
      *(float4*)&tv[0] = *(const float4*)&T2s[k][lg * 4];
      *(float4*)&tv[4] = *(const float4*)&T2s[k][128 + lg * 4];
#pragma unroll
      for (int i = 0; i < 8; ++i)
#pragma unroll
        for (int jj = 0; jj < 8; ++jj)
          acc[i][jj] = fmaf(av[i], tv[jj], acc[i][jj]);
    }
    __syncthreads();
  }

#pragma unroll
  for (int i = 0; i < 8; ++i) {
    float* dst = &y[((size_t)c0 + cg * 8 + i) * L_FFT + l0];
    *(float4*)(dst + lg * 4) =
        make_float4(acc[i][0], acc[i][1], acc[i][2], acc[i][3]);
    *(float4*)(dst + 128 + lg * 4) =
        make_float4(acc[i][4], acc[i][5], acc[i][6], acc[i][7]);
  }
}

// ---------------------------------------------------------------------------
extern "C" void kernel_launch(void* const* d_in, const int* in_sizes, int n_in,
                              void* d_out, int out_size, void* d_ws, size_t ws_size,
                              hipStream_t stream) {
  const float* q   = (const float*)d_in[0];
  const float* wre = (const float*)d_in[4];
  const float* wim = (const float*)d_in[5];
  const int* index = (const int*)d_in[6];
  float* y = (float*)d_out;
  float* ws = (float*)d_ws;

  // ws layout (floats): T1 [4096*128] | T2 [128*4096] | A [8192*128] | g [8192*128] | part [np*8192*128]
  float* T1 = ws;
  float* T2 = ws + 524288;
  float* A  = ws + 1048576;
  float* g  = ws + 2097152;
  const size_t base_floats = 3145728;  // 12 MB

  int np = 1;
  while (np < 8) {
    size_t need = (base_floats + (size_t)(np * 2) * 1048576ull) * 4ull;
    if (need <= ws_size) np *= 2; else break;
  }
  float* part = (np == 1) ? g : (ws + base_floats);
  int kspan = L_FFT / np;

  k0_tables<<<dim3(1024), dim3(256), 0, stream>>>(index, T1, T2);
  k1_forward<<<dim3(64, np), dim3(256), 0, stream>>>(q, T1, part, kspan);
  if (np > 1)
    k1b_reduce<<<dim3(4096), dim3(256), 0, stream>>>(part, g, np);
  k2_mix<<<dim3(16, 8, 16), dim3(256), 0, stream>>>(g, wre, wim, A);
  k3_inverse<<<dim3(16, 128), dim3(256), 0, stream>>>(A, T2, y);
}